// Round 1
// baseline (217.968 us; speedup 1.0000x reference)
//
#include <hip/hip_runtime.h>
#include <hip/hip_bf16.h>

// Problem dims
constexpr int BDIM = 16384;  // B
constexpr int LDIM = 4096;   // L
constexpr int HDIM = 1024;   // H (K of the GEMM)

// GEMM tile config (m97 structure: 128x128 tile, BK=32, 4 waves, dbuf LDS)
constexpr int BM = 128;
constexpr int BN = 128;
constexpr int BK = 32;

typedef __bf16 bf16_t;
typedef __attribute__((ext_vector_type(8))) __bf16 bf16x8;
typedef __attribute__((ext_vector_type(4))) float f32x4;

// ---------- fp32 -> bf16 (RNE) ----------
__device__ __forceinline__ unsigned short f2bf(float f) {
  unsigned int u = __float_as_uint(f);
  u += 0x7fffu + ((u >> 16) & 1u);
  return (unsigned short)(u >> 16);
}

// Convert A [B*H] and W [L*H] fp32 -> bf16 into workspace. float4 reads, 8B writes.
__global__ void cvt_kernel(const float* __restrict__ A, const float* __restrict__ W,
                           unsigned short* __restrict__ Ab, unsigned short* __restrict__ Wb,
                           int nA, int nW) {
  const int nA4 = nA >> 2;
  const int total = (nA + nW) >> 2;
  for (int i = blockIdx.x * blockDim.x + threadIdx.x; i < total;
       i += gridDim.x * blockDim.x) {
    const float4* src;
    unsigned short* dst;
    int j;
    if (i < nA4) { src = (const float4*)A; dst = Ab; j = i; }
    else         { src = (const float4*)W; dst = Wb; j = i - nA4; }
    float4 v = src[j];
    ushort4 r;
    r.x = f2bf(v.x); r.y = f2bf(v.y); r.z = f2bf(v.z); r.w = f2bf(v.w);
    ((ushort4*)dst)[j] = r;
  }
}

// ---------- label_bias[j] = W[j] . E[j] + b[j], exact fp32 ----------
// one wave per row; 256 threads = 4 rows per block
__global__ void bias_kernel(const float* __restrict__ W, const float* __restrict__ E,
                            const float* __restrict__ b, float* __restrict__ bias) {
  const int w = threadIdx.x >> 6;
  const int l = threadIdx.x & 63;
  const int row = blockIdx.x * 4 + w;
  const float4* Wr = (const float4*)(W + (size_t)row * HDIM);
  const float4* Er = (const float4*)(E + (size_t)row * HDIM);
  float s = 0.0f;
#pragma unroll
  for (int i = 0; i < HDIM / 256; ++i) {  // 4 iters: 64 lanes * 4 floats
    float4 wv = Wr[i * 64 + l];
    float4 ev = Er[i * 64 + l];
    s += wv.x * ev.x + wv.y * ev.y + wv.z * ev.z + wv.w * ev.w;
  }
#pragma unroll
  for (int o = 32; o > 0; o >>= 1) s += __shfl_down(s, o, 64);
  if (l == 0) bias[row] = s + b[row];
}

// ---------- GEMM: C[B,L] = Ab[B,H] * Wb[L,H]^T + bias[L] ----------
__device__ __forceinline__ void gld_lds16(const void* g, void* l) {
  __builtin_amdgcn_global_load_lds(
      (const __attribute__((address_space(1))) void*)g,
      (__attribute__((address_space(3))) void*)l, 16, 0, 0);
}

__global__ __launch_bounds__(256) void gemm_kernel(
    const unsigned short* __restrict__ Ab,  // [BDIM, HDIM] bf16
    const unsigned short* __restrict__ Wb,  // [LDIM, HDIM] bf16
    const float* __restrict__ bias,         // [LDIM]
    float* __restrict__ C)                  // [BDIM, LDIM]
{
  __shared__ unsigned short As[2][BM * BK];  // 8 KiB each buf
  __shared__ unsigned short Bs[2][BN * BK];

  const int tid = threadIdx.x;
  const int w = tid >> 6;   // wave 0..3
  const int l = tid & 63;

  // XCD-aware swizzle: 4096 blocks, 8 XCDs, nwg % 8 == 0 -> simple form is bijective
  const int nwg = gridDim.x;
  const int bid = blockIdx.x;
  const int swz = (bid & 7) * (nwg >> 3) + (bid >> 3);
  const int nblk = swz & 31;   // 32 N-blocks
  const int mblk = swz >> 5;   // 128 M-blocks
  const int brow = mblk * BM;
  const int bcol = nblk * BN;

  const int wr = w >> 1, wc = w & 1;      // 2x2 wave grid, each wave 64x64 out
  const int lr = l & 15;                  // fragment row/col lane index
  const int lk = (l >> 4) << 3;           // k-offset within BK=32

  // staging: wave w issues 4x 1KiB chunks; bytes [0,8K)=A-tile, [8K,16K)=B-tile
  const int srow = l >> 2;                // 0..15 within 16-row group
  const int scol = (l & 3) << 3;          // 0,8,16,24 (x8 bf16 = 16B)

  f32x4 acc[4][4] = {};

#define STAGE(buf, k0)                                                         \
  {                                                                            \
    _Pragma("unroll")                                                          \
    for (int i = 0; i < 4; ++i) {                                              \
      const int off = (w * 4 + i) * 1024;                                      \
      if (off < 8192) {                                                        \
        const int row = (off >> 6) + srow;                                     \
        gld_lds16(Ab + (size_t)(brow + row) * HDIM + (k0) + scol,              \
                  &As[buf][off >> 1]);                                         \
      } else {                                                                 \
        const int boff = off - 8192;                                           \
        const int row = (boff >> 6) + srow;                                    \
        gld_lds16(Wb + (size_t)(bcol + row) * HDIM + (k0) + scol,              \
                  &Bs[buf][boff >> 1]);                                        \
      }                                                                        \
    }                                                                          \
  }

#define COMPUTE(buf)                                                           \
  {                                                                            \
    bf16x8 aF[4], bF[4];                                                       \
    _Pragma("unroll")                                                          \
    for (int mi = 0; mi < 4; ++mi)                                             \
      aF[mi] = *(const bf16x8*)&As[buf][(wr * 64 + mi * 16 + lr) * BK + lk];   \
    _Pragma("unroll")                                                          \
    for (int ni = 0; ni < 4; ++ni)                                             \
      bF[ni] = *(const bf16x8*)&Bs[buf][(wc * 64 + ni * 16 + lr) * BK + lk];   \
    _Pragma("unroll")                                                          \
    for (int mi = 0; mi < 4; ++mi) {                                           \
      _Pragma("unroll")                                                        \
      for (int ni = 0; ni < 4; ++ni)                                           \
        acc[mi][ni] = __builtin_amdgcn_mfma_f32_16x16x32_bf16(                 \
            aF[mi], bF[ni], acc[mi][ni], 0, 0, 0);                             \
    }                                                                          \
  }

  int cur = 0;
  STAGE(0, 0);
  __syncthreads();

  constexpr int KT = HDIM / BK;  // 32
  for (int kt = 0; kt < KT - 1; ++kt) {
    const int k0 = (kt + 1) * BK;
    STAGE(cur ^ 1, k0);
    COMPUTE(cur);
    __syncthreads();
    cur ^= 1;
  }
  COMPUTE(cur);

  // epilogue: add bias[col], store fp32
  float bv[4];
#pragma unroll
  for (int ni = 0; ni < 4; ++ni) bv[ni] = bias[bcol + wc * 64 + ni * 16 + lr];

  const int orow0 = brow + wr * 64 + (l >> 4) * 4;
  const int ocol0 = bcol + wc * 64 + lr;
#pragma unroll
  for (int mi = 0; mi < 4; ++mi) {
#pragma unroll
    for (int ni = 0; ni < 4; ++ni) {
#pragma unroll
      for (int r = 0; r < 4; ++r) {
        const int rr = orow0 + mi * 16 + r;
        const int cc = ocol0 + ni * 16;
        C[(size_t)rr * LDIM + cc] = acc[mi][ni][r] + bv[ni];
      }
    }
  }
#undef STAGE
#undef COMPUTE
}

extern "C" void kernel_launch(void* const* d_in, const int* in_sizes, int n_in,
                              void* d_out, int out_size, void* d_ws, size_t ws_size,
                              hipStream_t stream) {
  const float* bert = (const float*)d_in[0];  // [B,H]
  const float* emb  = (const float*)d_in[1];  // [L,H]
  const float* W    = (const float*)d_in[2];  // [L,H]
  const float* b    = (const float*)d_in[3];  // [L]
  float* out = (float*)d_out;

  // workspace layout: Ab (32 MiB) | Wb (8 MiB) | bias (16 KiB)
  char* ws = (char*)d_ws;
  unsigned short* Ab = (unsigned short*)ws;
  unsigned short* Wb = (unsigned short*)(ws + (size_t)BDIM * HDIM * 2);
  float* bias = (float*)(ws + (size_t)BDIM * HDIM * 2 + (size_t)LDIM * HDIM * 2);

  hipLaunchKernelGGL(cvt_kernel, dim3(2048), dim3(256), 0, stream,
                     bert, W, Ab, Wb, BDIM * HDIM, LDIM * HDIM);
  hipLaunchKernelGGL(bias_kernel, dim3(LDIM / 4), dim3(256), 0, stream,
                     W, emb, b, bias);
  hipLaunchKernelGGL(gemm_kernel, dim3((BDIM / BM) * (LDIM / BN)), dim3(256), 0, stream,
                     Ab, Wb, bias, out);
}

// Round 2
// 188.376 us; speedup vs baseline: 1.1571x; 1.1571x over previous
//
#include <hip/hip_runtime.h>
#include <hip/hip_bf16.h>

// Problem dims
constexpr int BDIM = 16384;  // B (GEMM M)
constexpr int LDIM = 4096;   // L (GEMM N)
constexpr int HDIM = 1024;   // H (GEMM K)

// GEMM tile config: 256x256 tile, BK=32, 8 waves (2Mx4N), 4-slot LDS ring
constexpr int BM = 256;
constexpr int BN = 256;
constexpr int BK = 32;

typedef __attribute__((ext_vector_type(8))) __bf16 bf16x8;
typedef __attribute__((ext_vector_type(4))) float f32x4;

// ---------- fp32 -> bf16 (RNE) ----------
__device__ __forceinline__ unsigned short f2bf(float f) {
  unsigned int u = __float_as_uint(f);
  u += 0x7fffu + ((u >> 16) & 1u);
  return (unsigned short)(u >> 16);
}

__global__ void cvt_kernel(const float* __restrict__ A, const float* __restrict__ W,
                           unsigned short* __restrict__ Ab, unsigned short* __restrict__ Wb,
                           int nA, int nW) {
  const int nA4 = nA >> 2;
  const int total = (nA + nW) >> 2;
  for (int i = blockIdx.x * blockDim.x + threadIdx.x; i < total;
       i += gridDim.x * blockDim.x) {
    const float4* src;
    unsigned short* dst;
    int j;
    if (i < nA4) { src = (const float4*)A; dst = Ab; j = i; }
    else         { src = (const float4*)W; dst = Wb; j = i - nA4; }
    float4 v = src[j];
    ushort4 r;
    r.x = f2bf(v.x); r.y = f2bf(v.y); r.z = f2bf(v.z); r.w = f2bf(v.w);
    ((ushort4*)dst)[j] = r;
  }
}

// ---------- label_bias[j] = W[j] . E[j] + b[j], exact fp32 ----------
__global__ void bias_kernel(const float* __restrict__ W, const float* __restrict__ E,
                            const float* __restrict__ b, float* __restrict__ bias) {
  const int w = threadIdx.x >> 6;
  const int l = threadIdx.x & 63;
  const int row = blockIdx.x * 4 + w;
  const float4* Wr = (const float4*)(W + (size_t)row * HDIM);
  const float4* Er = (const float4*)(E + (size_t)row * HDIM);
  float s = 0.0f;
#pragma unroll
  for (int i = 0; i < HDIM / 256; ++i) {
    float4 wv = Wr[i * 64 + l];
    float4 ev = Er[i * 64 + l];
    s += wv.x * ev.x + wv.y * ev.y + wv.z * ev.z + wv.w * ev.w;
  }
#pragma unroll
  for (int o = 32; o > 0; o >>= 1) s += __shfl_down(s, o, 64);
  if (l == 0) bias[row] = s + b[row];
}

// ---------- GEMM: C[B,L] = Ab[B,H] * Wb[L,H]^T + bias[L] ----------
__device__ __forceinline__ void gld_lds16(const void* g, void* l) {
  __builtin_amdgcn_global_load_lds(
      (const __attribute__((address_space(1))) void*)g,
      (__attribute__((address_space(3))) void*)l, 16, 0, 0);
}

#define VM8 asm volatile("s_waitcnt vmcnt(8)" ::: "memory")
#define VM4 asm volatile("s_waitcnt vmcnt(4)" ::: "memory")
#define VM0 asm volatile("s_waitcnt vmcnt(0)" ::: "memory")
#define VMNONE (void)0

__global__ __launch_bounds__(512, 2) void gemm_kernel(
    const unsigned short* __restrict__ Ab,  // [BDIM, HDIM] bf16
    const unsigned short* __restrict__ Wb,  // [LDIM, HDIM] bf16
    const float* __restrict__ bias,         // [LDIM]
    float* __restrict__ C)                  // [BDIM, LDIM]
{
  // 4-slot ring, each slot: 256 rows x 32 cols bf16 = 16 KiB. 64 KiB per matrix.
  __shared__ unsigned short As[4 * BM * BK];  // 64 KiB
  __shared__ unsigned short Bs[4 * BN * BK];  // 64 KiB

  const int tid = threadIdx.x;
  const int w = tid >> 6;      // wave 0..7
  const int l = tid & 63;
  const int wr = w >> 2;       // 0..1 : M half (128 rows)
  const int wc = w & 3;        // 0..3 : N quarter (64 cols)

  // XCD-aware swizzle (1024 blocks, %8==0 -> bijective)
  const int bid = blockIdx.x;
  const int swz = (bid & 7) * 128 + (bid >> 3);
  const int mblk = swz >> 4;   // 64 M-blocks
  const int nblk = swz & 15;   // 16 N-blocks
  const int brow = mblk * BM;
  const int bcol = nblk * BN;

  // --- staging constants ---
  // each global_load_lds: 512 thr x 16B = 8 KiB = 128 rows of 64B
  // thread t: row = t>>2 (0..127), lds chunk = t&3; source chunk pre-swizzled:
  const int srow = tid >> 2;
  const int sc = (tid & 3) ^ ((tid >> 3) & 3);   // chunk ^ ((row>>1)&3)
  const unsigned short* aSrc = Ab + (size_t)(brow + srow) * HDIM + sc * 8;
  const unsigned short* bSrc = Wb + (size_t)(bcol + srow) * HDIM + sc * 8;

  // --- fragment-read constants (swizzled ds_read addresses, in shorts) ---
  const int lr = l & 15;
  const int lc = (lr >> 1) & 3;
  const int rdA = (wr * 128 + lr) * BK + (((l >> 4) ^ lc) << 3);
  const int rdB = (wc * 64 + lr) * BK + (((l >> 4) ^ lc) << 3);

  f32x4 acc[8][4] = {};

  // issue one matrix's K-tile (2 x 8KiB halves). slot/dest wave-uniform.
#define ISSUE_A(t, s)                                                          \
  { gld_lds16(aSrc + (size_t)(t) * BK, &As[(s) * 8192 + w * 512]);             \
    gld_lds16(aSrc + (size_t)(t) * BK + (size_t)128 * HDIM,                    \
              &As[(s) * 8192 + 4096 + w * 512]); }
#define ISSUE_B(t, s)                                                          \
  { gld_lds16(bSrc + (size_t)(t) * BK, &Bs[(s) * 8192 + w * 512]);             \
    gld_lds16(bSrc + (size_t)(t) * BK + (size_t)128 * HDIM,                    \
              &Bs[(s) * 8192 + 4096 + w * 512]); }

#define MFMA_QUAD(AA, BB, mbase)                                               \
  _Pragma("unroll") for (int mi = 0; mi < 4; ++mi) {                           \
    _Pragma("unroll") for (int ni = 0; ni < 4; ++ni)                           \
      acc[(mbase) + mi][ni] = __builtin_amdgcn_mfma_f32_16x16x32_bf16(         \
          AA[mi], BB[ni], acc[(mbase) + mi][ni], 0, 0, 0);                     \
  }

  // one K-tile = 2 phases x 16 MFMA; issues tile t3's A at P0, B at P1.
#define TILE_BODY(s, doiss, t3, s3, VMWAIT, LASTBAR)                           \
  {                                                                            \
    if (doiss) ISSUE_A((t3), (s3));                                            \
    __builtin_amdgcn_sched_barrier(0);                                         \
    bf16x8 bfr[4], afr[4];                                                     \
    _Pragma("unroll") for (int ni = 0; ni < 4; ++ni)                           \
      bfr[ni] = *(const bf16x8*)&Bs[(s) * 8192 + rdB + ni * 512];              \
    _Pragma("unroll") for (int mi = 0; mi < 4; ++mi)                           \
      afr[mi] = *(const bf16x8*)&As[(s) * 8192 + rdA + mi * 512];              \
    __builtin_amdgcn_s_setprio(1);                                             \
    MFMA_QUAD(afr, bfr, 0)                                                     \
    __builtin_amdgcn_s_setprio(0);                                             \
    __builtin_amdgcn_s_barrier();                                              \
    asm volatile("" ::: "memory");                                             \
    if (doiss) ISSUE_B((t3), (s3));                                            \
    __builtin_amdgcn_sched_barrier(0);                                         \
    _Pragma("unroll") for (int mi = 0; mi < 4; ++mi)                           \
      afr[mi] = *(const bf16x8*)&As[(s) * 8192 + rdA + 2048 + mi * 512];       \
    __builtin_amdgcn_s_setprio(1);                                             \
    MFMA_QUAD(afr, bfr, 4)                                                     \
    __builtin_amdgcn_s_setprio(0);                                             \
    VMWAIT;                                                                    \
    if (LASTBAR) __builtin_amdgcn_s_barrier();                                 \
    asm volatile("" ::: "memory");                                             \
  }

  // prologue: stage tiles 0,1,2 into slots 0,1,2
  ISSUE_A(0, 0); ISSUE_B(0, 0);
  ISSUE_A(1, 1); ISSUE_B(1, 1);
  ISSUE_A(2, 2); ISSUE_B(2, 2);
  VM8;  // tile 0 landed (8 younger stay in flight)
  __builtin_amdgcn_s_barrier();
  asm volatile("" ::: "memory");

  // main: tiles 0..27, issuing tiles 3..30 (3 K-tiles / 12 loads in flight)
  for (int t = 0; t < 28; t += 4) {
    TILE_BODY(0, true, t + 3, 3, VM8, true);
    TILE_BODY(1, true, t + 4, 0, VM8, true);
    TILE_BODY(2, true, t + 5, 1, VM8, true);
    TILE_BODY(3, true, t + 6, 2, VM8, true);
  }
  // peel: tiles 28..31 (issue 31; drain ring with counted waits)
  TILE_BODY(0, true, 31, 3, VM8, true);
  TILE_BODY(1, false, 0, 0, VM4, true);
  TILE_BODY(2, false, 0, 0, VM0, true);
  TILE_BODY(3, false, 0, 0, VMNONE, false);

  // epilogue: add bias[col], store fp32
  float bv[4];
#pragma unroll
  for (int ni = 0; ni < 4; ++ni) bv[ni] = bias[bcol + wc * 64 + ni * 16 + lr];

  const int orow0 = brow + wr * 128 + (l >> 4) * 4;
  const int ocol0 = bcol + wc * 64 + lr;
#pragma unroll
  for (int mi = 0; mi < 8; ++mi) {
#pragma unroll
    for (int ni = 0; ni < 4; ++ni) {
#pragma unroll
      for (int r = 0; r < 4; ++r) {
        C[(size_t)(orow0 + mi * 16 + r) * LDIM + ocol0 + ni * 16] =
            acc[mi][ni][r] + bv[ni];
      }
    }
  }
#undef TILE_BODY
#undef MFMA_QUAD
#undef ISSUE_A
#undef ISSUE_B
}

extern "C" void kernel_launch(void* const* d_in, const int* in_sizes, int n_in,
                              void* d_out, int out_size, void* d_ws, size_t ws_size,
                              hipStream_t stream) {
  const float* bert = (const float*)d_in[0];  // [B,H]
  const float* emb  = (const float*)d_in[1];  // [L,H]
  const float* W    = (const float*)d_in[2];  // [L,H]
  const float* b    = (const float*)d_in[3];  // [L]
  float* out = (float*)d_out;

  char* ws = (char*)d_ws;
  unsigned short* Ab = (unsigned short*)ws;
  unsigned short* Wb = (unsigned short*)(ws + (size_t)BDIM * HDIM * 2);
  float* bias = (float*)(ws + (size_t)BDIM * HDIM * 2 + (size_t)LDIM * HDIM * 2);

  hipLaunchKernelGGL(cvt_kernel, dim3(2048), dim3(256), 0, stream,
                     bert, W, Ab, Wb, BDIM * HDIM, LDIM * HDIM);
  hipLaunchKernelGGL(bias_kernel, dim3(LDIM / 4), dim3(256), 0, stream,
                     W, emb, b, bias);
  hipLaunchKernelGGL(gemm_kernel, dim3((BDIM / BM) * (LDIM / BN)), dim3(512), 0, stream,
                     Ab, Wb, bias, out);
}

// Round 3
// 187.088 us; speedup vs baseline: 1.1651x; 1.0069x over previous
//
#include <hip/hip_runtime.h>
#include <hip/hip_bf16.h>

// Problem dims
constexpr int BDIM = 16384;  // B (GEMM M)
constexpr int LDIM = 4096;   // L (GEMM N)
constexpr int HDIM = 1024;   // H (GEMM K)

// GEMM tile config: m201-style 256x256 tile, BK=64, 8 waves (2Mx4N), 2-deep dbuf
constexpr int BM = 256;
constexpr int BN = 256;
constexpr int BK = 64;
constexpr int KTILES = HDIM / BK;  // 16

typedef __attribute__((ext_vector_type(8))) __bf16 bf16x8;
typedef __attribute__((ext_vector_type(4))) float f32x4;

// ---------- fp32 -> bf16 (RNE) ----------
__device__ __forceinline__ unsigned short f2bf(float f) {
  unsigned int u = __float_as_uint(f);
  u += 0x7fffu + ((u >> 16) & 1u);
  return (unsigned short)(u >> 16);
}

__global__ void cvt_kernel(const float* __restrict__ A, const float* __restrict__ W,
                           unsigned short* __restrict__ Ab, unsigned short* __restrict__ Wb,
                           int nA, int nW) {
  const int nA4 = nA >> 2;
  const int total = (nA + nW) >> 2;
  for (int i = blockIdx.x * blockDim.x + threadIdx.x; i < total;
       i += gridDim.x * blockDim.x) {
    const float4* src;
    unsigned short* dst;
    int j;
    if (i < nA4) { src = (const float4*)A; dst = Ab; j = i; }
    else         { src = (const float4*)W; dst = Wb; j = i - nA4; }
    float4 v = src[j];
    ushort4 r;
    r.x = f2bf(v.x); r.y = f2bf(v.y); r.z = f2bf(v.z); r.w = f2bf(v.w);
    ((ushort4*)dst)[j] = r;
  }
}

// ---------- label_bias[j] = W[j] . E[j] + b[j], exact fp32 ----------
__global__ void bias_kernel(const float* __restrict__ W, const float* __restrict__ E,
                            const float* __restrict__ b, float* __restrict__ bias) {
  const int w = threadIdx.x >> 6;
  const int l = threadIdx.x & 63;
  const int row = blockIdx.x * 4 + w;
  const float4* Wr = (const float4*)(W + (size_t)row * HDIM);
  const float4* Er = (const float4*)(E + (size_t)row * HDIM);
  float s = 0.0f;
#pragma unroll
  for (int i = 0; i < HDIM / 256; ++i) {
    float4 wv = Wr[i * 64 + l];
    float4 ev = Er[i * 64 + l];
    s += wv.x * ev.x + wv.y * ev.y + wv.z * ev.z + wv.w * ev.w;
  }
#pragma unroll
  for (int o = 32; o > 0; o >>= 1) s += __shfl_down(s, o, 64);
  if (l == 0) bias[row] = s + b[row];
}

// ---------- GEMM: C[B,L] = Ab[B,H] * Wb[L,H]^T + bias[L] ----------
__device__ __forceinline__ void gld_lds16(const void* g, void* l) {
  __builtin_amdgcn_global_load_lds(
      (const __attribute__((address_space(1))) void*)g,
      (__attribute__((address_space(3))) void*)l, 16, 0, 0);
}

#define MEMPIN asm volatile("" ::: "memory")
#define BAR __builtin_amdgcn_s_barrier()
#define LGKM0 asm volatile("s_waitcnt lgkmcnt(0)" ::: "memory")
#define VM4 asm volatile("s_waitcnt vmcnt(4)" ::: "memory")
#define VM0 asm volatile("s_waitcnt vmcnt(0)" ::: "memory")
#define VMNONE (void)0

__global__ __launch_bounds__(512, 2) void gemm_kernel(
    const unsigned short* __restrict__ Ab,  // [BDIM, HDIM] bf16
    const unsigned short* __restrict__ Wb,  // [LDIM, HDIM] bf16
    const float* __restrict__ bias,         // [LDIM]
    float* __restrict__ C)                  // [BDIM, LDIM]
{
  // 2-deep dbuf, each: 256 rows x 64 cols bf16 = 32 KiB. 64 KiB per matrix.
  __shared__ unsigned short As[2 * BM * BK];  // 64 KiB
  __shared__ unsigned short Bs[2 * BN * BK];  // 64 KiB

  const int tid = threadIdx.x;
  const int w = tid >> 6;      // wave 0..7
  const int l = tid & 63;
  const int wr = w >> 2;       // 0..1 : M half (128 rows)
  const int wc = w & 3;        // 0..3 : N quarter (64 cols)
  const int lr = l & 15;
  const int hi = l >> 4;

  // XCD-aware swizzle (1024 blocks, %8==0 -> bijective)
  const int bid = blockIdx.x;
  const int swz = (bid & 7) * 128 + (bid >> 3);
  const int mblk = swz >> 4;   // 64 M-blocks
  const int nblk = swz & 15;   // 16 N-blocks
  const int brow = mblk * BM;
  const int bcol = nblk * BN;

  // --- staging source (per thread). One gload_lds = 512thr x 16B = 8 KiB
  //     = 64 rows x 64 cols. thread t: row=t>>3, chunk=t&7; source chunk
  //     pre-swizzled by chunk ^ (row&7) (zero-conflict involution).
  const int srow = tid >> 3;                    // 0..63
  const int scn = (tid & 7) ^ (srow & 7);
  const unsigned short* aSrc = Ab + (size_t)(brow + srow) * HDIM + scn * 8;
  const unsigned short* bSrc = Wb + (size_t)(bcol + srow) * HDIM + scn * 8;
  const int wdst = w * 512;                     // wave-uniform LDS dest (shorts)

  // --- fragment-read constants (swizzled chunk offsets, shorts) ---
  const int c0 = ((hi) ^ (lr & 7)) * 8;         // k-slice 0 (k=0..31)
  const int c1 = ((4 + hi) ^ (lr & 7)) * 8;     // k-slice 1 (k=32..63)
  const int rowA = wr * 128 + lr;
  const int rowB = wc * 64 + lr;

  f32x4 acc[8][4] = {};
  bf16x8 aF[8];            // current A m-half: [mi0..3][ks0..1]
  bf16x8 bF0[4], bF1[4];   // B n-halves g0 (ni0..1) / g1 (ni2..3), [ni][ks]

#define ISSUE_A(d, h, tk)                                                      \
  { const unsigned short* s_ = aSrc + (size_t)((h) * 128) * HDIM + (tk) * BK;  \
    unsigned short* p_ = &As[(d) * 16384 + (h) * 8192 + wdst];                 \
    gld_lds16(s_, p_);                                                         \
    gld_lds16(s_ + (size_t)64 * HDIM, p_ + 4096); }
#define ISSUE_B(d, h, tk)                                                      \
  { const unsigned short* s_ = bSrc + (size_t)((h) * 128) * HDIM + (tk) * BK;  \
    unsigned short* p_ = &Bs[(d) * 16384 + (h) * 8192 + wdst];                 \
    gld_lds16(s_, p_);                                                         \
    gld_lds16(s_ + (size_t)64 * HDIM, p_ + 4096); }

#define READ_A(d, h)                                                           \
  _Pragma("unroll") for (int mi = 0; mi < 4; ++mi) {                           \
    const int r_ = (d) * 16384 + (rowA + (h) * 64 + mi * 16) * BK;             \
    aF[mi * 2 + 0] = *(const bf16x8*)&As[r_ + c0];                             \
    aF[mi * 2 + 1] = *(const bf16x8*)&As[r_ + c1];                             \
  }
#define READ_B(d, g, BF)                                                       \
  _Pragma("unroll") for (int ni = 0; ni < 2; ++ni) {                           \
    const int r_ = (d) * 16384 + (rowB + (g) * 32 + ni * 16) * BK;             \
    BF[ni * 2 + 0] = *(const bf16x8*)&Bs[r_ + c0];                             \
    BF[ni * 2 + 1] = *(const bf16x8*)&Bs[r_ + c1];                             \
  }

#define MQUAD(h, g, BF)                                                        \
  __builtin_amdgcn_s_setprio(1);                                               \
  _Pragma("unroll") for (int mi = 0; mi < 4; ++mi) {                           \
    _Pragma("unroll") for (int ni = 0; ni < 2; ++ni) {                         \
      acc[(h) * 4 + mi][(g) * 2 + ni] = __builtin_amdgcn_mfma_f32_16x16x32_bf16( \
          aF[mi * 2 + 0], BF[ni * 2 + 0], acc[(h) * 4 + mi][(g) * 2 + ni], 0, 0, 0); \
      acc[(h) * 4 + mi][(g) * 2 + ni] = __builtin_amdgcn_mfma_f32_16x16x32_bf16( \
          aF[mi * 2 + 1], BF[ni * 2 + 1], acc[(h) * 4 + mi][(g) * 2 + ni], 0, 0, 0); \
    }                                                                          \
  }                                                                            \
  __builtin_amdgcn_s_setprio(0);

  // Per tile t (buf d): P1 stages A(t+1).h0 -> d^1, P2 stages A(t+1).h1,
  // P3 stages B(t+2).h0 -> d (B of d free after P2), P4 stages B(t+2).h1.
  // vmcnt(4) once per tile at P4 drains A(t+1)+older, leaves B(t+2) in flight.
#define TILE(d, t, SA, SB, VMW)                                                \
  { /* P1: reads A.h0(8) + B.g0(4), MFMA quadrant (h0,g0) */                   \
    READ_A(d, 0) READ_B(d, 0, bF0)                                             \
    if (SA) ISSUE_A((d) ^ 1, 0, (t) + 1);                                      \
    MEMPIN; BAR; LGKM0;                                                        \
    MQUAD(0, 0, bF0)                                                           \
    MEMPIN; BAR;                                                               \
    /* P2: reads B.g1(4), MFMA (h0,g1) */                                      \
    READ_B(d, 1, bF1)                                                          \
    if (SA) ISSUE_A((d) ^ 1, 1, (t) + 1);                                      \
    MEMPIN; BAR; LGKM0;                                                        \
    MQUAD(0, 1, bF1)                                                           \
    MEMPIN; BAR;                                                               \
    /* P3: reads A.h1(8), MFMA (h1,g1) */                                      \
    READ_A(d, 1)                                                               \
    if (SB) ISSUE_B((d), 0, (t) + 2);                                          \
    MEMPIN; BAR; LGKM0;                                                        \
    MQUAD(1, 1, bF1)                                                           \
    MEMPIN; BAR;                                                               \
    /* P4: no reads (bF0 reused), MFMA (h1,g0), counted vmcnt */               \
    if (SB) ISSUE_B((d), 1, (t) + 2);                                          \
    MEMPIN; BAR;                                                               \
    MQUAD(1, 0, bF0)                                                           \
    VMW;                                                                       \
    MEMPIN; BAR;                                                               \
  }

  // prologue: tile0 (A+B, buf0) + B(1) (buf1) = 12 loads; drain tile0 only.
  ISSUE_A(0, 0, 0); ISSUE_A(0, 1, 0);
  ISSUE_B(0, 0, 0); ISSUE_B(0, 1, 0);
  ISSUE_B(1, 0, 1); ISSUE_B(1, 1, 1);
  VM4;
  MEMPIN; BAR;

#pragma unroll 1
  for (int t = 0; t < KTILES - 2; t += 2) {
    TILE(0, t, 1, 1, VM4);
    TILE(1, t + 1, 1, 1, VM4);
  }
  TILE(0, KTILES - 2, 1, 0, VM0);   // stages A(15); drains everything
  TILE(1, KTILES - 1, 0, 0, VMNONE);

  // epilogue: add bias[col], store fp32
  float bv[4];
#pragma unroll
  for (int ni = 0; ni < 4; ++ni) bv[ni] = bias[bcol + wc * 64 + ni * 16 + lr];

  const int orow0 = brow + wr * 128 + hi * 4;
  const int ocol0 = bcol + wc * 64 + lr;
#pragma unroll
  for (int mi = 0; mi < 8; ++mi) {
#pragma unroll
    for (int ni = 0; ni < 4; ++ni) {
#pragma unroll
      for (int r = 0; r < 4; ++r) {
        C[(size_t)(orow0 + mi * 16 + r) * LDIM + ocol0 + ni * 16] =
            acc[mi][ni][r] + bv[ni];
      }
    }
  }
#undef TILE
#undef MQUAD
#undef READ_A
#undef READ_B
#undef ISSUE_A
#undef ISSUE_B
}

extern "C" void kernel_launch(void* const* d_in, const int* in_sizes, int n_in,
                              void* d_out, int out_size, void* d_ws, size_t ws_size,
                              hipStream_t stream) {
  const float* bert = (const float*)d_in[0];  // [B,H]
  const float* emb  = (const float*)d_in[1];  // [L,H]
  const float* W    = (const float*)d_in[2];  // [L,H]
  const float* b    = (const float*)d_in[3];  // [L]
  float* out = (float*)d_out;

  char* ws = (char*)d_ws;
  unsigned short* Ab = (unsigned short*)ws;
  unsigned short* Wb = (unsigned short*)(ws + (size_t)BDIM * HDIM * 2);
  float* bias = (float*)(ws + (size_t)BDIM * HDIM * 2 + (size_t)LDIM * HDIM * 2);

  hipLaunchKernelGGL(cvt_kernel, dim3(2048), dim3(256), 0, stream,
                     bert, W, Ab, Wb, BDIM * HDIM, LDIM * HDIM);
  hipLaunchKernelGGL(bias_kernel, dim3(LDIM / 4), dim3(256), 0, stream,
                     W, emb, b, bias);
  hipLaunchKernelGGL(gemm_kernel, dim3((BDIM / BM) * (LDIM / BN)), dim3(512), 0, stream,
                     Ab, Wb, bias, out);
}